// Round 24
// baseline (440.420 us; speedup 1.0000x reference)
//
#include <hip/hip_runtime.h>

// ---------------------------------------------------------------------------
// SemanticMemoryLatentSpace, fully factored (see R7 header).
// R23: prep dispatch eliminated. u computed just-in-time inside scan wave2
// (exact prep order -> bitwise-identical), Kpart moved into fused_gemms
// (blocks 448-511). 3 dispatches: fused_gemms, scan, final.
// Scan body otherwise identical to R22 (190us).
// ---------------------------------------------------------------------------

#define A_BOOSTF 0.012247448713915891f // 1.5*alpha (growth==0 always)

template <int CTRL>
__device__ __forceinline__ float dpp_f(float x) {
  return __int_as_float(
      __builtin_amdgcn_mov_dpp(__float_as_int(x), CTRL, 0xf, 0xf, true));
}
template <int CTRL>
__device__ __forceinline__ unsigned dpp_u(unsigned x) {
  return (unsigned)__builtin_amdgcn_mov_dpp((int)x, CTRL, 0xf, 0xf, true);
}
__device__ __forceinline__ float rdlane_f(float x, int l) {
  return __int_as_float(__builtin_amdgcn_readlane(__float_as_int(x), l));
}
__device__ __forceinline__ unsigned rdlane_u(unsigned x, int l) {
  return (unsigned)__builtin_amdgcn_readlane((int)x, l);
}
__device__ __forceinline__ float wave_sum64(float v) {
  v += dpp_f<0xB1>(v);
  v += dpp_f<0x4E>(v);
  v += dpp_f<0x124>(v);
  v += dpp_f<0x128>(v);
  return (rdlane_f(v, 0) + rdlane_f(v, 16)) + (rdlane_f(v, 32) + rdlane_f(v, 48));
}
__device__ __forceinline__ unsigned sortable(float v) {
  unsigned u = __float_as_uint(v);
  return u ^ (unsigned)(((int)u >> 31) | 0x80000000);
}
__device__ __forceinline__ float unsortable(unsigned x) {
  unsigned u = (x & 0x80000000u) ? (x ^ 0x80000000u) : ~x;
  return __uint_as_float(u);
}
__device__ __forceinline__ unsigned wave_umax64(unsigned v) {
  v = max(v, dpp_u<0xB1>(v));
  v = max(v, dpp_u<0x4E>(v));
  v = max(v, dpp_u<0x124>(v));
  v = max(v, dpp_u<0x128>(v));
  return max(max(rdlane_u(v, 0), rdlane_u(v, 16)),
             max(rdlane_u(v, 32), rdlane_u(v, 48)));
}

#define GX(D)                                                                  \
  ((D) < 4 ? ((D) == 0   ? gq[0].x                                             \
              : (D) == 1 ? gq[0].y                                             \
              : (D) == 2 ? gq[0].z                                             \
                         : gq[0].w)                                            \
   : (D) < 8                                                                   \
       ? ((D) == 4   ? gq[1].x                                                 \
          : (D) == 5 ? gq[1].y                                                 \
          : (D) == 6 ? gq[1].z                                                 \
                     : gq[1].w)                                                \
   : (D) < 12 ? ((D) == 8    ? gq[2].x                                         \
                 : (D) == 9  ? gq[2].y                                         \
                 : (D) == 10 ? gq[2].z                                         \
                             : gq[2].w)                                        \
              : ((D) == 12   ? gq[3].x                                         \
                 : (D) == 13 ? gq[3].y                                         \
                 : (D) == 14 ? gq[3].z                                         \
                             : gq[3].w))

// ---- fused: G = E E^T (0..255) | M0 = E K0 (256..447) | Kpart (448..511) ---
__global__ __launch_bounds__(256) void fused_gemms(const float* __restrict__ E,
                                                   const float* __restrict__ K0,
                                                   float* __restrict__ G,
                                                   float* __restrict__ M0,
                                                   float* __restrict__ Kpart) {
  __shared__ float As[32][33];
  __shared__ float Bs[32][33];
  const int b = blockIdx.x;
  const int tid = threadIdx.x;
  const int tx = tid & 15, ty = tid >> 4;

  if (b < 256) {
    const int bx = b & 15, by = b >> 4;
    float a00 = 0.f, a01 = 0.f, a10 = 0.f, a11 = 0.f;
    for (int k0 = 0; k0 < 384; k0 += 32) {
      for (int l = tid; l < 1024; l += 256) {
        int r = l >> 5, c = l & 31;
        As[r][c] = E[(by * 32 + r) * 384 + k0 + c];
        Bs[r][c] = E[(bx * 32 + r) * 384 + k0 + c];
      }
      __syncthreads();
#pragma unroll
      for (int k = 0; k < 32; ++k) {
        float x0 = As[2 * ty][k], x1 = As[2 * ty + 1][k];
        float y0 = Bs[2 * tx][k], y1 = Bs[2 * tx + 1][k];
        a00 += x0 * y0; a01 += x0 * y1; a10 += x1 * y0; a11 += x1 * y1;
      }
      __syncthreads();
    }
    int i = by * 32 + 2 * ty, jj = bx * 32 + 2 * tx;
    G[i * 512 + jj] = a00;           G[i * 512 + jj + 1] = a01;
    G[(i + 1) * 512 + jj] = a10;     G[(i + 1) * 512 + jj + 1] = a11;
  } else if (b < 448) {
    const int bb = b - 256;
    const int bx = bb % 12, by = bb / 12;
    float a00 = 0.f, a01 = 0.f, a10 = 0.f, a11 = 0.f;
    for (int k0 = 0; k0 < 384; k0 += 32) {
      for (int l = tid; l < 1024; l += 256) {
        int r = l >> 5, c = l & 31;
        As[r][c] = E[(by * 32 + r) * 384 + k0 + c];
        Bs[r][c] = K0[(k0 + r) * 384 + bx * 32 + c];
      }
      __syncthreads();
#pragma unroll
      for (int k = 0; k < 32; ++k) {
        float x0 = As[2 * ty][k], x1 = As[2 * ty + 1][k];
        float y0 = Bs[k][2 * tx], y1 = Bs[k][2 * tx + 1];
        a00 += x0 * y0; a01 += x0 * y1; a10 += x1 * y0; a11 += x1 * y1;
      }
      __syncthreads();
    }
    int i = by * 32 + 2 * ty, jj = bx * 32 + 2 * tx;
    M0[i * 384 + jj] = a00;           M0[i * 384 + jj + 1] = a01;
    M0[(i + 1) * 384 + jj] = a10;     M0[(i + 1) * 384 + jj + 1] = a11;
  } else {
    __shared__ double wr[4];
    const int cb = b - 448;
    const int lane = tid & 63, wv = tid >> 6;
    const float* p = K0 + cb * 2304 + tid * 9;
    double acc = 0.0;
#pragma unroll
    for (int i = 0; i < 9; ++i) { double v = (double)p[i]; acc += v * v; }
#pragma unroll
    for (int off = 32; off; off >>= 1) acc += __shfl_down(acc, off);
    if (lane == 0) wr[wv] = acc;
    __syncthreads();
    if (tid == 0) Kpart[cb] = (float)(wr[0] + wr[1] + wr[2] + wr[3]);
  }
}

// out[i][j] = g*M0[i][j] + sum_s G[i][s]*W[s]*E[s][j]
__global__ __launch_bounds__(256) void final_gemm(const float* __restrict__ G,
                                                  const float* __restrict__ E,
                                                  const float* __restrict__ M0,
                                                  const float* __restrict__ W,
                                                  const float* __restrict__ gS,
                                                  float* __restrict__ out) {
  __shared__ float As[32][33];
  __shared__ float Bs[32][33];
  int bx = blockIdx.x, by = blockIdx.y;
  int tid = threadIdx.x;
  int tx = tid & 15, ty = tid >> 4;
  float a00 = 0.f, a01 = 0.f, a10 = 0.f, a11 = 0.f;
  for (int k0 = 0; k0 < 512; k0 += 32) {
    for (int l = tid; l < 1024; l += 256) {
      int r = l >> 5, c = l & 31;
      As[r][c] = G[(by * 32 + r) * 512 + k0 + c] * W[k0 + c];
      Bs[r][c] = E[(k0 + r) * 384 + bx * 32 + c];
    }
    __syncthreads();
#pragma unroll
    for (int k = 0; k < 32; ++k) {
      float x0 = As[2 * ty][k], x1 = As[2 * ty + 1][k];
      float y0 = Bs[k][2 * tx], y1 = Bs[k][2 * tx + 1];
      a00 += x0 * y0; a01 += x0 * y1; a10 += x1 * y0; a11 += x1 * y1;
    }
    __syncthreads();
  }
  float gv = gS[0];
  int i = by * 32 + 2 * ty, jj = bx * 32 + 2 * tx;
  out[i * 384 + jj]         = gv * M0[i * 384 + jj]         + a00;
  out[i * 384 + jj + 1]     = gv * M0[i * 384 + jj + 1]     + a01;
  out[(i + 1) * 384 + jj]     = gv * M0[(i + 1) * 384 + jj]     + a10;
  out[(i + 1) * 384 + jj + 1] = gv * M0[(i + 1) * 384 + jj + 1] + a11;
}

// ---------------- three-wave scan (u computed in wave2, JIT) ----------------
__global__ __launch_bounds__(192) void scan_kernel(const float* __restrict__ G,
                                                   const float* __restrict__ E,
                                                   const float* __restrict__ M0,
                                                   const float* __restrict__ Kpart,
                                                   float* __restrict__ Wout,
                                                   float* __restrict__ gOut) {
  __shared__ float RAW[100 * 257];
  __shared__ float gx_tbl[512 * 16];
  __shared__ float ren_tbl[512];
  __shared__ float wh_sh[512];
  __shared__ float RG_bnew[512];
  __shared__ float RG_nov[512];
  __shared__ int RG_idx[512];
  __shared__ int FLAG;
  __shared__ int FLAG2;
  __shared__ int FLAG3A;
  __shared__ int FLAG3B;

  const int tid = threadIdx.x;
  const int wid = tid >> 6;
  const int lane = tid & 63;

  float4 z4 = {0.f, 0.f, 0.f, 0.f};
  for (int i = tid; i < 6425; i += 192) ((float4*)RAW)[i] = z4;
  for (int tt = tid; tt < 512; tt += 192) {
    const float* gr = G + tt * 512 + tt;
    const int lim = 512 - tt;
#pragma unroll
    for (int d = 0; d < 16; ++d)
      gx_tbl[tt * 16 + d] = (d < lim) ? gr[d] : 0.f;
    ren_tbl[tt] = __builtin_amdgcn_rcpf(__builtin_amdgcn_sqrtf(gr[0]));
  }
  if (tid == 0) { FLAG = 0; FLAG2 = -1; FLAG3A = 0; FLAG3B = 0; }
  __syncthreads();

  if (wid == 0) {
    float d0 = 1.f, d1 = 1.f, cn0 = 0.f, cn1 = 0.f, s0 = 0.f, s1 = 0.f;
    int nact = 0;
    float r0[8], r1[8];
#pragma unroll
    for (int j = 0; j < 8; ++j) { r0[j] = 0.f; r1[j] = 0.f; }

    const float4* gx4 = (const float4*)gx_tbl;
    float4 gq[4];
    float renk;
    gq[0] = gx4[0]; gq[1] = gx4[1]; gq[2] = gx4[2]; gq[3] = gx4[3];
    renk = ren_tbl[0];

#define W0STEP(K)                                                              \
    {                                                                          \
      const int tnx = (t + (K) + 1 < 512) ? t + (K) + 1 : 511;                 \
      float4 gqn0 = gx4[tnx * 4], gqn1 = gx4[tnx * 4 + 1];                     \
      float4 gqn2 = gx4[tnx * 4 + 2], gqn3 = gx4[tnx * 4 + 3];                 \
      float renn = ren_tbl[tnx];                                               \
      const float trk = gq[0].x;                                               \
      float v0 = (lane < nact) ? s0 * renk * r0[K] : -2.f;                     \
      float v1 = (lane + 64 < nact) ? s1 * renk * r1[K] : -2.f;                \
      unsigned pk0 = (sortable(v0) & ~127u) | (unsigned)(127 - lane);          \
      unsigned pk1 = (sortable(v1) & ~127u) | (unsigned)(63 - lane);           \
      unsigned P = wave_umax64(max(pk0, pk1));                                 \
      int imax = 127 - (int)(P & 127u);                                        \
      float M = unsortable(P & ~127u);                                         \
      float nov = (nact == 0) ? 1.f : fminf(1.f, fmaxf(0.f, 1.f - M * M));     \
      int create = (nov > 0.7f && nact < 100) ? 1 : 0;                         \
      const int idxs = create ? nact : imax;                                   \
      const int cl = idxs & 63, hi = idxs >> 6;                                \
      float dcA = create ? 1.f : 0.95f * d0;                                   \
      float dcB = create ? 1.f : 0.95f * d1;                                   \
      float ccA = create ? trk                                                 \
                         : (0.9025f * cn0 + 0.095f * (d0 * r0[K]) +            \
                            0.0025f * trk);                                    \
      float ccB = create ? trk                                                 \
                         : (0.9025f * cn1 + 0.095f * (d1 * r1[K]) +            \
                            0.0025f * trk);                                    \
      float scA = dcA * __builtin_amdgcn_rcpf(__builtin_amdgcn_sqrtf(ccA));    \
      float scB = dcB * __builtin_amdgcn_rcpf(__builtin_amdgcn_sqrtf(ccB));    \
      float ivA = 0.05f * __builtin_amdgcn_rcpf(dcA);                          \
      float ivB = 0.05f * __builtin_amdgcn_rcpf(dcB);                          \
      bool own0 = (lane == cl) && (hi == 0);                                   \
      bool own1 = (lane == cl) && (hi == 1);                                   \
      d0 = own0 ? dcA : d0; cn0 = own0 ? ccA : cn0; s0 = own0 ? scA : s0;      \
      d1 = own1 ? dcB : d1; cn1 = own1 ? ccB : cn1; s1 = own1 ? scB : s1;      \
      float bnew = create ? 1.f : rdlane_f(hi ? ivB : ivA, cl);                \
      nact += create;                                                          \
      float pb0 = own0 ? bnew : 0.f, pb1 = own1 ? bnew : 0.f;                  \
      _Pragma("unroll") for (int j = (K) + 1; j < 8; ++j) {                    \
        r0[j] += pb0 * GX((j) - (K));                                          \
        r1[j] += pb1 * GX((j) - (K));                                          \
      }                                                                        \
      _Pragma("unroll") for (int j = 0; j < 8; ++j) {                          \
        pa0[j] += pb0 * GX(8 + (j) - (K));                                     \
        pa1[j] += pb1 * GX(8 + (j) - (K));                                     \
      }                                                                        \
      bnewA[K] = bnew; novA[K] = nov; idxA[K] = idxs;                          \
      gq[0] = gqn0; gq[1] = gqn1; gq[2] = gqn2; gq[3] = gqn3;                  \
      renk = renn;                                                             \
    }

    for (int R = 0; R < 64; ++R) {
      const int t = 8 * R;
      const int tn = t + 8;
      const int cnx = tn & 255;

      if (t == 256) {
        while (__hip_atomic_load(&FLAG3A, __ATOMIC_ACQUIRE,
                                 __HIP_MEMORY_SCOPE_WORKGROUP) == 0)
          __builtin_amdgcn_s_sleep(1);
        while (__hip_atomic_load(&FLAG3B, __ATOMIC_ACQUIRE,
                                 __HIP_MEMORY_SCOPE_WORKGROUP) == 0)
          __builtin_amdgcn_s_sleep(1);
#pragma unroll
        for (int j = 0; j < 8; ++j) r0[j] = RAW[lane * 257 + j];
        if (lane < 36) {
#pragma unroll
          for (int j = 0; j < 8; ++j) r1[j] = RAW[(lane + 64) * 257 + j];
        }
        __builtin_amdgcn_sched_barrier(0);
      }

      float bnewA[8], novA[8];
      int idxA[8];
      float pa0[8], pa1[8];
#pragma unroll
      for (int j = 0; j < 8; ++j) { pa0[j] = 0.f; pa1[j] = 0.f; }

      W0STEP(0) W0STEP(1) W0STEP(2) W0STEP(3)
      W0STEP(4) W0STEP(5) W0STEP(6) W0STEP(7)

      if (tn < 512 && cnx != 0) {
        while (__hip_atomic_load(&FLAG2, __ATOMIC_ACQUIRE,
                                 __HIP_MEMORY_SCOPE_WORKGROUP) < R - 1)
          __builtin_amdgcn_s_sleep(1);
        float r0n[8], r1n[8];
#pragma unroll
        for (int j = 0; j < 8; ++j) r0n[j] = RAW[lane * 257 + cnx + j];
        if (lane < 36) {
#pragma unroll
          for (int j = 0; j < 8; ++j) r1n[j] = RAW[(lane + 64) * 257 + cnx + j];
        } else {
#pragma unroll
          for (int j = 0; j < 8; ++j) r1n[j] = 0.f;
        }
#pragma unroll
        for (int j = 0; j < 8; ++j) {
          r0[j] = r0n[j] + pa0[j];
          r1[j] = r1n[j] + pa1[j];
        }
      }
      __builtin_amdgcn_sched_barrier(0);

      if (lane == 0) {
#pragma unroll
        for (int k = 0; k < 8; ++k) {
          RG_bnew[t + k] = bnewA[k];
          RG_nov[t + k] = novA[k];
          RG_idx[t + k] = idxA[k];
        }
        __hip_atomic_store(&FLAG, R + 1, __ATOMIC_RELEASE,
                           __HIP_MEMORY_SCOPE_WORKGROUP);
      }
    }
#undef W0STEP
  } else if (wid == 1) {
    for (int r = 0; r < 64; ++r) {
      const int t = 8 * r;
      const int c = t & 255;
      const int gbase = (t >> 6) & ~3;

      float B4[8][4];
#pragma unroll
      for (int k = 0; k < 8; ++k)
#pragma unroll
        for (int mg = 0; mg < 4; ++mg)
          B4[k][mg] = G[(t + k) * 512 + (gbase + mg) * 64 + lane];

      while (__hip_atomic_load(&FLAG, __ATOMIC_ACQUIRE,
                               __HIP_MEMORY_SCOPE_WORKGROUP) < r + 1)
        __builtin_amdgcn_s_sleep(1);

      float bn[8];
      int id[8];
#pragma unroll
      for (int k = 0; k < 8; ++k) { bn[k] = RG_bnew[t + k]; id[k] = RG_idx[t + k]; }

#pragma unroll
      for (int k = 0; k < 8; ++k) {
#pragma unroll
        for (int mg = 0; mg < 4; ++mg)
          if (mg * 64 + 63 >= c) {
            const int a_ = id[k] * 257 + mg * 64 + lane;
            RAW[a_] += bn[k] * B4[k][mg];
          }
      }
      __hip_atomic_store(&FLAG2, r, __ATOMIC_RELEASE,
                         __HIP_MEMORY_SCOPE_WORKGROUP);

      if (r == 31) {
        for (int i = lane; i < 3212; i += 64) ((float4*)RAW)[i] = z4;
        if (lane < 2) RAW[12848 + lane] = 0.f;
        __builtin_amdgcn_sched_barrier(0);
        const float* Gb = G + 256;
        for (int s = 0; s < 256; s += 4) {
          float A[4][4], bh[4];
          int idj[4];
#pragma unroll
          for (int j = 0; j < 4; ++j) {
            bh[j] = RG_bnew[s + j]; idj[j] = RG_idx[s + j];
#pragma unroll
            for (int m = 0; m < 4; ++m)
              A[j][m] = Gb[(s + j) * 512 + m * 64 + lane];
          }
#pragma unroll
          for (int j = 0; j < 4; ++j) {
            if (idj[j] < 50) {
#pragma unroll
              for (int m = 0; m < 4; ++m) {
                const int a_ = idj[j] * 257 + m * 64 + lane;
                RAW[a_] += bh[j] * A[j][m];
              }
            }
          }
        }
        __builtin_amdgcn_sched_barrier(0);
        __hip_atomic_store(&FLAG3A, 1, __ATOMIC_RELEASE,
                           __HIP_MEMORY_SCOPE_WORKGROUP);
      }
    }
  } else {
    // ================== WAVE 2: lag chain + JIT u + rebuild 50-99 ==========
    float q8[8];
#pragma unroll
    for (int gI = 0; gI < 8; ++gI) q8[gI] = 0.f;
    float n2 = wave_sum64(Kpart[lane]);
    float g = 1.f, ginv = 1.f;

    for (int r = 0; r < 64; ++r) {
      const int t = 8 * r;

      if (r == 32) {
        while (__hip_atomic_load(&FLAG2, __ATOMIC_ACQUIRE,
                                 __HIP_MEMORY_SCOPE_WORKGROUP) < 31)
          __builtin_amdgcn_s_sleep(1);
        if (lane < 2) RAW[12850 + lane] = 0.f;
        for (int i = 3213 + lane; i < 6425; i += 64) ((float4*)RAW)[i] = z4;
        __builtin_amdgcn_sched_barrier(0);
        const float* Gb = G + 256;
        for (int s = 0; s < 256; s += 4) {
          float A[4][4], bh[4];
          int idj[4];
#pragma unroll
          for (int j = 0; j < 4; ++j) {
            bh[j] = RG_bnew[s + j]; idj[j] = RG_idx[s + j];
#pragma unroll
            for (int m = 0; m < 4; ++m)
              A[j][m] = Gb[(s + j) * 512 + m * 64 + lane];
          }
#pragma unroll
          for (int j = 0; j < 4; ++j) {
            if (idj[j] >= 50) {
#pragma unroll
              for (int m = 0; m < 4; ++m) {
                const int a_ = idj[j] * 257 + m * 64 + lane;
                RAW[a_] += bh[j] * A[j][m];
              }
            }
          }
        }
        __builtin_amdgcn_sched_barrier(0);
        __hip_atomic_store(&FLAG3B, 1, __ATOMIC_RELEASE,
                           __HIP_MEMORY_SCOPE_WORKGROUP);
      }

      // JIT u for rows t..t+7 (exact prep order -> bitwise-identical)
      float um[8];
#pragma unroll
      for (int k = 0; k < 8; ++k) {
        const int row = t + k;
        const float4* e4 = (const float4*)(E + row * 384);
        const float4* m4 = (const float4*)(M0 + row * 384);
        float p = 0.f;
        {
          float4 a = e4[lane], bb = m4[lane];
          p += a.x * bb.x + a.y * bb.y + a.z * bb.z + a.w * bb.w;
        }
        if (lane < 32) {
          float4 a = e4[lane + 64], bb = m4[lane + 64];
          p += a.x * bb.x + a.y * bb.y + a.z * bb.z + a.w * bb.w;
        }
#pragma unroll
        for (int off = 32; off; off >>= 1) p += __shfl_down(p, off);
        um[k] = rdlane_f(p, 0);
      }

      float B[8][8];
#pragma unroll
      for (int k = 0; k < 8; ++k)
#pragma unroll
        for (int gI = 0; gI < 8; ++gI)
          B[k][gI] = G[(t + k) * 512 + gI * 64 + lane];

      while (__hip_atomic_load(&FLAG, __ATOMIC_ACQUIRE,
                               __HIP_MEMORY_SCOPE_WORKGROUP) < r + 1)
        __builtin_amdgcn_s_sleep(1);

      float novv[8];
#pragma unroll
      for (int k = 0; k < 8; ++k) novv[k] = RG_nov[t + k];

      float trm[8], gxw[8][8];
#pragma unroll
      for (int m = 0; m < 8; ++m) {
        trm[m] = gx_tbl[(t + m) * 16];
#pragma unroll
        for (int j = m + 1; j < 8; ++j)
          gxw[m][j] = gx_tbl[(t + m) * 16 + (j - m)];
      }

      const int grp = t >> 6;
      float qsel = q8[0];
#pragma unroll
      for (int gI = 1; gI < 8; ++gI) qsel = (grp == gI) ? q8[gI] : qsel;
      float qeff[8];
#pragma unroll
      for (int k = 0; k < 8; ++k) qeff[k] = rdlane_f(qsel, (t & 63) + k);

      float wh[8];
#pragma unroll
      for (int m = 0; m < 8; ++m) {
        float nov = novv[m];
        float iw = nov * __builtin_amdgcn_sqrtf(nov);
        float psc = 384.0f * __builtin_amdgcn_rcpf(fmaxf(trm[m], 1e-8f));
        float ccf = A_BOOSTF * iw * psc;
        float qv = g * (um[m] + qeff[m]);
        float n2n = n2 + 2.f * ccf * qv + ccf * ccf * trm[m] * trm[m];
        float kn = __builtin_amdgcn_sqrtf(n2n);
        float fct = (kn > 50.f) ? 50.f * __builtin_amdgcn_rcpf(kn) : 1.f;
        float fiv = (kn > 50.f) ? kn * 0.02f : 1.f;
        wh[m] = ccf * ginv;
        n2 = n2n * fct * fct; g *= fct; ginv *= fiv;
#pragma unroll
        for (int j = m + 1; j < 8; ++j)
          qeff[j] += wh[m] * gxw[m][j] * gxw[m][j];
      }

      if (lane == 0) {
#pragma unroll
        for (int m = 0; m < 8; ++m) wh_sh[t + m] = wh[m];
      }
#pragma unroll
      for (int gI = 0; gI < 8; ++gI)
#pragma unroll
        for (int k = 0; k < 8; ++k)
          q8[gI] += wh[k] * B[k][gI] * B[k][gI];
    }

    for (int s2 = lane; s2 < 512; s2 += 64) Wout[s2] = wh_sh[s2] * g;
    if (lane == 0) gOut[0] = g;
  }
}

extern "C" void kernel_launch(void* const* d_in, const int* in_sizes, int n_in,
                              void* d_out, int out_size, void* d_ws,
                              size_t ws_size, hipStream_t stream) {
  const float* E = (const float*)d_in[0];   // [512,384]
  const float* K0 = (const float*)d_in[1];  // [384,384]
  float* out = (float*)d_out;               // [512,384]

  float* G = (float*)d_ws;                  // 512*512
  float* M0 = G + 512 * 512;                // 512*384
  float* W = M0 + 512 * 384;                // 512
  float* gS = W + 512;                      // 1
  float* Kpart = gS + 1;                    // 64

  fused_gemms<<<512, 256, 0, stream>>>(E, K0, G, M0, Kpart);
  scan_kernel<<<1, 192, 0, stream>>>(G, E, M0, Kpart, W, gS);
  final_gemm<<<dim3(12, 16), 256, 0, stream>>>(G, E, M0, W, gS, out);
}

// Round 25
// 245.690 us; speedup vs baseline: 1.7926x; 1.7926x over previous
//
#include <hip/hip_runtime.h>

// ---------------------------------------------------------------------------
// SemanticMemoryLatentSpace, fully factored (see R7 header).
// R24: REVERT to the best-known configuration (R23, 245.9us):
//   fused_gemms (G | M0, 448 blocks) -> prep (u, Kpart) -> 3-wave scan
//   (190us, chain floor 87us measured) -> final_gemm.
// R24's JIT-u-in-wave2 made wave2 critical (serial shfl trees behind cold
// loads): scan 190->435. Rule: the scan tolerates zero added global work.
// ---------------------------------------------------------------------------

#define A_BOOSTF 0.012247448713915891f // 1.5*alpha (growth==0 always)

template <int CTRL>
__device__ __forceinline__ float dpp_f(float x) {
  return __int_as_float(
      __builtin_amdgcn_mov_dpp(__float_as_int(x), CTRL, 0xf, 0xf, true));
}
template <int CTRL>
__device__ __forceinline__ unsigned dpp_u(unsigned x) {
  return (unsigned)__builtin_amdgcn_mov_dpp((int)x, CTRL, 0xf, 0xf, true);
}
__device__ __forceinline__ float rdlane_f(float x, int l) {
  return __int_as_float(__builtin_amdgcn_readlane(__float_as_int(x), l));
}
__device__ __forceinline__ unsigned rdlane_u(unsigned x, int l) {
  return (unsigned)__builtin_amdgcn_readlane((int)x, l);
}
__device__ __forceinline__ float wave_sum64(float v) {
  v += dpp_f<0xB1>(v);
  v += dpp_f<0x4E>(v);
  v += dpp_f<0x124>(v);
  v += dpp_f<0x128>(v);
  return (rdlane_f(v, 0) + rdlane_f(v, 16)) + (rdlane_f(v, 32) + rdlane_f(v, 48));
}
__device__ __forceinline__ unsigned sortable(float v) {
  unsigned u = __float_as_uint(v);
  return u ^ (unsigned)(((int)u >> 31) | 0x80000000);
}
__device__ __forceinline__ float unsortable(unsigned x) {
  unsigned u = (x & 0x80000000u) ? (x ^ 0x80000000u) : ~x;
  return __uint_as_float(u);
}
__device__ __forceinline__ unsigned wave_umax64(unsigned v) {
  v = max(v, dpp_u<0xB1>(v));
  v = max(v, dpp_u<0x4E>(v));
  v = max(v, dpp_u<0x124>(v));
  v = max(v, dpp_u<0x128>(v));
  return max(max(rdlane_u(v, 0), rdlane_u(v, 16)),
             max(rdlane_u(v, 32), rdlane_u(v, 48)));
}

#define GX(D)                                                                  \
  ((D) < 4 ? ((D) == 0   ? gq[0].x                                             \
              : (D) == 1 ? gq[0].y                                             \
              : (D) == 2 ? gq[0].z                                             \
                         : gq[0].w)                                            \
   : (D) < 8                                                                   \
       ? ((D) == 4   ? gq[1].x                                                 \
          : (D) == 5 ? gq[1].y                                                 \
          : (D) == 6 ? gq[1].z                                                 \
                     : gq[1].w)                                                \
   : (D) < 12 ? ((D) == 8    ? gq[2].x                                         \
                 : (D) == 9  ? gq[2].y                                         \
                 : (D) == 10 ? gq[2].z                                         \
                             : gq[2].w)                                        \
              : ((D) == 12   ? gq[3].x                                         \
                 : (D) == 13 ? gq[3].y                                         \
                 : (D) == 14 ? gq[3].z                                         \
                             : gq[3].w))

// ---------------- fused G = E E^T (blocks 0..255) | M0 = E K0 (256..447) ----
__global__ __launch_bounds__(256) void fused_gemms(const float* __restrict__ E,
                                                   const float* __restrict__ K0,
                                                   float* __restrict__ G,
                                                   float* __restrict__ M0) {
  __shared__ float As[32][33];
  __shared__ float Bs[32][33];
  const int b = blockIdx.x;
  const int tid = threadIdx.x;
  const int tx = tid & 15, ty = tid >> 4;
  float a00 = 0.f, a01 = 0.f, a10 = 0.f, a11 = 0.f;

  if (b < 256) {
    const int bx = b & 15, by = b >> 4;
    for (int k0 = 0; k0 < 384; k0 += 32) {
      for (int l = tid; l < 1024; l += 256) {
        int r = l >> 5, c = l & 31;
        As[r][c] = E[(by * 32 + r) * 384 + k0 + c];
        Bs[r][c] = E[(bx * 32 + r) * 384 + k0 + c];
      }
      __syncthreads();
#pragma unroll
      for (int k = 0; k < 32; ++k) {
        float x0 = As[2 * ty][k], x1 = As[2 * ty + 1][k];
        float y0 = Bs[2 * tx][k], y1 = Bs[2 * tx + 1][k];
        a00 += x0 * y0; a01 += x0 * y1; a10 += x1 * y0; a11 += x1 * y1;
      }
      __syncthreads();
    }
    int i = by * 32 + 2 * ty, jj = bx * 32 + 2 * tx;
    G[i * 512 + jj] = a00;           G[i * 512 + jj + 1] = a01;
    G[(i + 1) * 512 + jj] = a10;     G[(i + 1) * 512 + jj + 1] = a11;
  } else {
    const int bb = b - 256;
    const int bx = bb % 12, by = bb / 12;
    for (int k0 = 0; k0 < 384; k0 += 32) {
      for (int l = tid; l < 1024; l += 256) {
        int r = l >> 5, c = l & 31;
        As[r][c] = E[(by * 32 + r) * 384 + k0 + c];
        Bs[r][c] = K0[(k0 + r) * 384 + bx * 32 + c];
      }
      __syncthreads();
#pragma unroll
      for (int k = 0; k < 32; ++k) {
        float x0 = As[2 * ty][k], x1 = As[2 * ty + 1][k];
        float y0 = Bs[k][2 * tx], y1 = Bs[k][2 * tx + 1];
        a00 += x0 * y0; a01 += x0 * y1; a10 += x1 * y0; a11 += x1 * y1;
      }
      __syncthreads();
    }
    int i = by * 32 + 2 * ty, jj = bx * 32 + 2 * tx;
    M0[i * 384 + jj] = a00;           M0[i * 384 + jj + 1] = a01;
    M0[(i + 1) * 384 + jj] = a10;     M0[(i + 1) * 384 + jj + 1] = a11;
  }
}

// out[i][j] = g*M0[i][j] + sum_s G[i][s]*W[s]*E[s][j]
__global__ __launch_bounds__(256) void final_gemm(const float* __restrict__ G,
                                                  const float* __restrict__ E,
                                                  const float* __restrict__ M0,
                                                  const float* __restrict__ W,
                                                  const float* __restrict__ gS,
                                                  float* __restrict__ out) {
  __shared__ float As[32][33];
  __shared__ float Bs[32][33];
  int bx = blockIdx.x, by = blockIdx.y;
  int tid = threadIdx.x;
  int tx = tid & 15, ty = tid >> 4;
  float a00 = 0.f, a01 = 0.f, a10 = 0.f, a11 = 0.f;
  for (int k0 = 0; k0 < 512; k0 += 32) {
    for (int l = tid; l < 1024; l += 256) {
      int r = l >> 5, c = l & 31;
      As[r][c] = G[(by * 32 + r) * 512 + k0 + c] * W[k0 + c];
      Bs[r][c] = E[(k0 + r) * 384 + bx * 32 + c];
    }
    __syncthreads();
#pragma unroll
    for (int k = 0; k < 32; ++k) {
      float x0 = As[2 * ty][k], x1 = As[2 * ty + 1][k];
      float y0 = Bs[k][2 * tx], y1 = Bs[k][2 * tx + 1];
      a00 += x0 * y0; a01 += x0 * y1; a10 += x1 * y0; a11 += x1 * y1;
    }
    __syncthreads();
  }
  float gv = gS[0];
  int i = by * 32 + 2 * ty, jj = bx * 32 + 2 * tx;
  out[i * 384 + jj]         = gv * M0[i * 384 + jj]         + a00;
  out[i * 384 + jj + 1]     = gv * M0[i * 384 + jj + 1]     + a01;
  out[(i + 1) * 384 + jj]     = gv * M0[(i + 1) * 384 + jj]     + a10;
  out[(i + 1) * 384 + jj + 1] = gv * M0[(i + 1) * 384 + jj + 1] + a11;
}

__global__ __launch_bounds__(256) void prep_kernel(const float* __restrict__ E,
                                                   const float* __restrict__ M0,
                                                   const float* __restrict__ K0,
                                                   float* __restrict__ u,
                                                   float* __restrict__ Kpart) {
  __shared__ double wr[4];
  int b = blockIdx.x;
  int tid = threadIdx.x, lane = tid & 63, wv = tid >> 6;
  if (b < 128) {
    int row = b * 4 + wv;
    const float4* e4 = (const float4*)(E + row * 384);
    const float4* m4 = (const float4*)(M0 + row * 384);
    float p = 0.f;
    for (int i = lane; i < 96; i += 64) {
      float4 a = e4[i], bb = m4[i];
      p += a.x * bb.x + a.y * bb.y + a.z * bb.z + a.w * bb.w;
    }
#pragma unroll
    for (int off = 32; off; off >>= 1) p += __shfl_down(p, off);
    if (lane == 0) u[row] = p;
  } else {
    int cb = b - 128;
    const float* p = K0 + cb * 2304 + tid * 9;
    double acc = 0.0;
#pragma unroll
    for (int i = 0; i < 9; ++i) { double v = (double)p[i]; acc += v * v; }
#pragma unroll
    for (int off = 32; off; off >>= 1) acc += __shfl_down(acc, off);
    if (lane == 0) wr[wv] = acc;
    __syncthreads();
    if (tid == 0) Kpart[cb] = (float)(wr[0] + wr[1] + wr[2] + wr[3]);
  }
}

// ---------------- three-wave scan (identical to R20/R23) --------------------
__global__ __launch_bounds__(192) void scan_kernel(const float* __restrict__ G,
                                                   const float* __restrict__ u,
                                                   const float* __restrict__ Kpart,
                                                   float* __restrict__ Wout,
                                                   float* __restrict__ gOut) {
  __shared__ float RAW[100 * 257];
  __shared__ float gx_tbl[512 * 16];
  __shared__ float ren_tbl[512];
  __shared__ float u_sh[512];
  __shared__ float wh_sh[512];
  __shared__ float RG_bnew[512];
  __shared__ float RG_nov[512];
  __shared__ int RG_idx[512];
  __shared__ int FLAG;
  __shared__ int FLAG2;
  __shared__ int FLAG3A;
  __shared__ int FLAG3B;

  const int tid = threadIdx.x;
  const int wid = tid >> 6;
  const int lane = tid & 63;

  float4 z4 = {0.f, 0.f, 0.f, 0.f};
  for (int i = tid; i < 6425; i += 192) ((float4*)RAW)[i] = z4;
  for (int tt = tid; tt < 512; tt += 192) {
    const float* gr = G + tt * 512 + tt;
    const int lim = 512 - tt;
#pragma unroll
    for (int d = 0; d < 16; ++d)
      gx_tbl[tt * 16 + d] = (d < lim) ? gr[d] : 0.f;
    ren_tbl[tt] = __builtin_amdgcn_rcpf(__builtin_amdgcn_sqrtf(gr[0]));
  }
  if (tid < 128) ((float4*)u_sh)[tid] = ((const float4*)u)[tid];
  if (tid == 0) { FLAG = 0; FLAG2 = -1; FLAG3A = 0; FLAG3B = 0; }
  __syncthreads();

  if (wid == 0) {
    float d0 = 1.f, d1 = 1.f, cn0 = 0.f, cn1 = 0.f, s0 = 0.f, s1 = 0.f;
    int nact = 0;
    float r0[8], r1[8];
#pragma unroll
    for (int j = 0; j < 8; ++j) { r0[j] = 0.f; r1[j] = 0.f; }

    const float4* gx4 = (const float4*)gx_tbl;
    float4 gq[4];
    float renk;
    gq[0] = gx4[0]; gq[1] = gx4[1]; gq[2] = gx4[2]; gq[3] = gx4[3];
    renk = ren_tbl[0];

#define W0STEP(K)                                                              \
    {                                                                          \
      const int tnx = (t + (K) + 1 < 512) ? t + (K) + 1 : 511;                 \
      float4 gqn0 = gx4[tnx * 4], gqn1 = gx4[tnx * 4 + 1];                     \
      float4 gqn2 = gx4[tnx * 4 + 2], gqn3 = gx4[tnx * 4 + 3];                 \
      float renn = ren_tbl[tnx];                                               \
      const float trk = gq[0].x;                                               \
      float v0 = (lane < nact) ? s0 * renk * r0[K] : -2.f;                     \
      float v1 = (lane + 64 < nact) ? s1 * renk * r1[K] : -2.f;                \
      unsigned pk0 = (sortable(v0) & ~127u) | (unsigned)(127 - lane);          \
      unsigned pk1 = (sortable(v1) & ~127u) | (unsigned)(63 - lane);           \
      unsigned P = wave_umax64(max(pk0, pk1));                                 \
      int imax = 127 - (int)(P & 127u);                                        \
      float M = unsortable(P & ~127u);                                         \
      float nov = (nact == 0) ? 1.f : fminf(1.f, fmaxf(0.f, 1.f - M * M));     \
      int create = (nov > 0.7f && nact < 100) ? 1 : 0;                         \
      const int idxs = create ? nact : imax;                                   \
      const int cl = idxs & 63, hi = idxs >> 6;                                \
      float dcA = create ? 1.f : 0.95f * d0;                                   \
      float dcB = create ? 1.f : 0.95f * d1;                                   \
      float ccA = create ? trk                                                 \
                         : (0.9025f * cn0 + 0.095f * (d0 * r0[K]) +            \
                            0.0025f * trk);                                    \
      float ccB = create ? trk                                                 \
                         : (0.9025f * cn1 + 0.095f * (d1 * r1[K]) +            \
                            0.0025f * trk);                                    \
      float scA = dcA * __builtin_amdgcn_rcpf(__builtin_amdgcn_sqrtf(ccA));    \
      float scB = dcB * __builtin_amdgcn_rcpf(__builtin_amdgcn_sqrtf(ccB));    \
      float ivA = 0.05f * __builtin_amdgcn_rcpf(dcA);                          \
      float ivB = 0.05f * __builtin_amdgcn_rcpf(dcB);                          \
      bool own0 = (lane == cl) && (hi == 0);                                   \
      bool own1 = (lane == cl) && (hi == 1);                                   \
      d0 = own0 ? dcA : d0; cn0 = own0 ? ccA : cn0; s0 = own0 ? scA : s0;      \
      d1 = own1 ? dcB : d1; cn1 = own1 ? ccB : cn1; s1 = own1 ? scB : s1;      \
      float bnew = create ? 1.f : rdlane_f(hi ? ivB : ivA, cl);                \
      nact += create;                                                          \
      float pb0 = own0 ? bnew : 0.f, pb1 = own1 ? bnew : 0.f;                  \
      _Pragma("unroll") for (int j = (K) + 1; j < 8; ++j) {                    \
        r0[j] += pb0 * GX((j) - (K));                                          \
        r1[j] += pb1 * GX((j) - (K));                                          \
      }                                                                        \
      _Pragma("unroll") for (int j = 0; j < 8; ++j) {                          \
        pa0[j] += pb0 * GX(8 + (j) - (K));                                     \
        pa1[j] += pb1 * GX(8 + (j) - (K));                                     \
      }                                                                        \
      bnewA[K] = bnew; novA[K] = nov; idxA[K] = idxs;                          \
      gq[0] = gqn0; gq[1] = gqn1; gq[2] = gqn2; gq[3] = gqn3;                  \
      renk = renn;                                                             \
    }

    for (int R = 0; R < 64; ++R) {
      const int t = 8 * R;
      const int tn = t + 8;
      const int cnx = tn & 255;

      if (t == 256) {
        while (__hip_atomic_load(&FLAG3A, __ATOMIC_ACQUIRE,
                                 __HIP_MEMORY_SCOPE_WORKGROUP) == 0)
          __builtin_amdgcn_s_sleep(1);
        while (__hip_atomic_load(&FLAG3B, __ATOMIC_ACQUIRE,
                                 __HIP_MEMORY_SCOPE_WORKGROUP) == 0)
          __builtin_amdgcn_s_sleep(1);
#pragma unroll
        for (int j = 0; j < 8; ++j) r0[j] = RAW[lane * 257 + j];
        if (lane < 36) {
#pragma unroll
          for (int j = 0; j < 8; ++j) r1[j] = RAW[(lane + 64) * 257 + j];
        }
        __builtin_amdgcn_sched_barrier(0);
      }

      float bnewA[8], novA[8];
      int idxA[8];
      float pa0[8], pa1[8];
#pragma unroll
      for (int j = 0; j < 8; ++j) { pa0[j] = 0.f; pa1[j] = 0.f; }

      W0STEP(0) W0STEP(1) W0STEP(2) W0STEP(3)
      W0STEP(4) W0STEP(5) W0STEP(6) W0STEP(7)

      if (tn < 512 && cnx != 0) {
        while (__hip_atomic_load(&FLAG2, __ATOMIC_ACQUIRE,
                                 __HIP_MEMORY_SCOPE_WORKGROUP) < R - 1)
          __builtin_amdgcn_s_sleep(1);
        float r0n[8], r1n[8];
#pragma unroll
        for (int j = 0; j < 8; ++j) r0n[j] = RAW[lane * 257 + cnx + j];
        if (lane < 36) {
#pragma unroll
          for (int j = 0; j < 8; ++j) r1n[j] = RAW[(lane + 64) * 257 + cnx + j];
        } else {
#pragma unroll
          for (int j = 0; j < 8; ++j) r1n[j] = 0.f;
        }
#pragma unroll
        for (int j = 0; j < 8; ++j) {
          r0[j] = r0n[j] + pa0[j];
          r1[j] = r1n[j] + pa1[j];
        }
      }
      __builtin_amdgcn_sched_barrier(0);

      if (lane == 0) {
#pragma unroll
        for (int k = 0; k < 8; ++k) {
          RG_bnew[t + k] = bnewA[k];
          RG_nov[t + k] = novA[k];
          RG_idx[t + k] = idxA[k];
        }
        __hip_atomic_store(&FLAG, R + 1, __ATOMIC_RELEASE,
                           __HIP_MEMORY_SCOPE_WORKGROUP);
      }
    }
#undef W0STEP
  } else if (wid == 1) {
    for (int r = 0; r < 64; ++r) {
      const int t = 8 * r;
      const int c = t & 255;
      const int gbase = (t >> 6) & ~3;

      float B4[8][4];
#pragma unroll
      for (int k = 0; k < 8; ++k)
#pragma unroll
        for (int mg = 0; mg < 4; ++mg)
          B4[k][mg] = G[(t + k) * 512 + (gbase + mg) * 64 + lane];

      while (__hip_atomic_load(&FLAG, __ATOMIC_ACQUIRE,
                               __HIP_MEMORY_SCOPE_WORKGROUP) < r + 1)
        __builtin_amdgcn_s_sleep(1);

      float bn[8];
      int id[8];
#pragma unroll
      for (int k = 0; k < 8; ++k) { bn[k] = RG_bnew[t + k]; id[k] = RG_idx[t + k]; }

#pragma unroll
      for (int k = 0; k < 8; ++k) {
#pragma unroll
        for (int mg = 0; mg < 4; ++mg)
          if (mg * 64 + 63 >= c) {
            const int a_ = id[k] * 257 + mg * 64 + lane;
            RAW[a_] += bn[k] * B4[k][mg];
          }
      }
      __hip_atomic_store(&FLAG2, r, __ATOMIC_RELEASE,
                         __HIP_MEMORY_SCOPE_WORKGROUP);

      if (r == 31) {
        for (int i = lane; i < 3212; i += 64) ((float4*)RAW)[i] = z4;
        if (lane < 2) RAW[12848 + lane] = 0.f;
        __builtin_amdgcn_sched_barrier(0);
        const float* Gb = G + 256;
        for (int s = 0; s < 256; s += 4) {
          float A[4][4], bh[4];
          int idj[4];
#pragma unroll
          for (int j = 0; j < 4; ++j) {
            bh[j] = RG_bnew[s + j]; idj[j] = RG_idx[s + j];
#pragma unroll
            for (int m = 0; m < 4; ++m)
              A[j][m] = Gb[(s + j) * 512 + m * 64 + lane];
          }
#pragma unroll
          for (int j = 0; j < 4; ++j) {
            if (idj[j] < 50) {
#pragma unroll
              for (int m = 0; m < 4; ++m) {
                const int a_ = idj[j] * 257 + m * 64 + lane;
                RAW[a_] += bh[j] * A[j][m];
              }
            }
          }
        }
        __builtin_amdgcn_sched_barrier(0);
        __hip_atomic_store(&FLAG3A, 1, __ATOMIC_RELEASE,
                           __HIP_MEMORY_SCOPE_WORKGROUP);
      }
    }
  } else {
    float q8[8];
#pragma unroll
    for (int gI = 0; gI < 8; ++gI) q8[gI] = 0.f;
    float n2 = wave_sum64(Kpart[lane]);
    float g = 1.f, ginv = 1.f;

    for (int r = 0; r < 64; ++r) {
      const int t = 8 * r;

      if (r == 32) {
        while (__hip_atomic_load(&FLAG2, __ATOMIC_ACQUIRE,
                                 __HIP_MEMORY_SCOPE_WORKGROUP) < 31)
          __builtin_amdgcn_s_sleep(1);
        if (lane < 2) RAW[12850 + lane] = 0.f;
        for (int i = 3213 + lane; i < 6425; i += 64) ((float4*)RAW)[i] = z4;
        __builtin_amdgcn_sched_barrier(0);
        const float* Gb = G + 256;
        for (int s = 0; s < 256; s += 4) {
          float A[4][4], bh[4];
          int idj[4];
#pragma unroll
          for (int j = 0; j < 4; ++j) {
            bh[j] = RG_bnew[s + j]; idj[j] = RG_idx[s + j];
#pragma unroll
            for (int m = 0; m < 4; ++m)
              A[j][m] = Gb[(s + j) * 512 + m * 64 + lane];
          }
#pragma unroll
          for (int j = 0; j < 4; ++j) {
            if (idj[j] >= 50) {
#pragma unroll
              for (int m = 0; m < 4; ++m) {
                const int a_ = idj[j] * 257 + m * 64 + lane;
                RAW[a_] += bh[j] * A[j][m];
              }
            }
          }
        }
        __builtin_amdgcn_sched_barrier(0);
        __hip_atomic_store(&FLAG3B, 1, __ATOMIC_RELEASE,
                           __HIP_MEMORY_SCOPE_WORKGROUP);
      }

      float B[8][8];
#pragma unroll
      for (int k = 0; k < 8; ++k)
#pragma unroll
        for (int gI = 0; gI < 8; ++gI)
          B[k][gI] = G[(t + k) * 512 + gI * 64 + lane];

      while (__hip_atomic_load(&FLAG, __ATOMIC_ACQUIRE,
                               __HIP_MEMORY_SCOPE_WORKGROUP) < r + 1)
        __builtin_amdgcn_s_sleep(1);

      float novv[8];
#pragma unroll
      for (int k = 0; k < 8; ++k) novv[k] = RG_nov[t + k];

      float trm[8], gxw[8][8];
#pragma unroll
      for (int m = 0; m < 8; ++m) {
        trm[m] = gx_tbl[(t + m) * 16];
#pragma unroll
        for (int j = m + 1; j < 8; ++j)
          gxw[m][j] = gx_tbl[(t + m) * 16 + (j - m)];
      }
      float4 uuA = *(const float4*)&u_sh[t];
      float4 uuB = *(const float4*)&u_sh[t + 4];
      float um[8] = {uuA.x, uuA.y, uuA.z, uuA.w, uuB.x, uuB.y, uuB.z, uuB.w};

      const int grp = t >> 6;
      float qsel = q8[0];
#pragma unroll
      for (int gI = 1; gI < 8; ++gI) qsel = (grp == gI) ? q8[gI] : qsel;
      float qeff[8];
#pragma unroll
      for (int k = 0; k < 8; ++k) qeff[k] = rdlane_f(qsel, (t & 63) + k);

      float wh[8];
#pragma unroll
      for (int m = 0; m < 8; ++m) {
        float nov = novv[m];
        float iw = nov * __builtin_amdgcn_sqrtf(nov);
        float psc = 384.0f * __builtin_amdgcn_rcpf(fmaxf(trm[m], 1e-8f));
        float ccf = A_BOOSTF * iw * psc;
        float qv = g * (um[m] + qeff[m]);
        float n2n = n2 + 2.f * ccf * qv + ccf * ccf * trm[m] * trm[m];
        float kn = __builtin_amdgcn_sqrtf(n2n);
        float fct = (kn > 50.f) ? 50.f * __builtin_amdgcn_rcpf(kn) : 1.f;
        float fiv = (kn > 50.f) ? kn * 0.02f : 1.f;
        wh[m] = ccf * ginv;
        n2 = n2n * fct * fct; g *= fct; ginv *= fiv;
#pragma unroll
        for (int j = m + 1; j < 8; ++j)
          qeff[j] += wh[m] * gxw[m][j] * gxw[m][j];
      }

      if (lane == 0) {
#pragma unroll
        for (int m = 0; m < 8; ++m) wh_sh[t + m] = wh[m];
      }
#pragma unroll
      for (int gI = 0; gI < 8; ++gI)
#pragma unroll
        for (int k = 0; k < 8; ++k)
          q8[gI] += wh[k] * B[k][gI] * B[k][gI];
    }

    for (int s2 = lane; s2 < 512; s2 += 64) Wout[s2] = wh_sh[s2] * g;
    if (lane == 0) gOut[0] = g;
  }
}

extern "C" void kernel_launch(void* const* d_in, const int* in_sizes, int n_in,
                              void* d_out, int out_size, void* d_ws,
                              size_t ws_size, hipStream_t stream) {
  const float* E = (const float*)d_in[0];   // [512,384]
  const float* K0 = (const float*)d_in[1];  // [384,384]
  float* out = (float*)d_out;               // [512,384]

  float* G = (float*)d_ws;                  // 512*512
  float* M0 = G + 512 * 512;                // 512*384
  float* u = M0 + 512 * 384;                // 512
  float* W = u + 512;                       // 512
  float* gS = W + 512;                      // 1
  float* Kpart = gS + 1;                    // 64

  fused_gemms<<<448, 256, 0, stream>>>(E, K0, G, M0);
  prep_kernel<<<192, 256, 0, stream>>>(E, M0, K0, u, Kpart);
  scan_kernel<<<1, 192, 0, stream>>>(G, u, Kpart, W, gS);
  final_gemm<<<dim3(12, 16), 256, 0, stream>>>(G, E, M0, W, gS, out);
}